// Round 1
// baseline (1715.616 us; speedup 1.0000x reference)
//
#include <hip/hip_runtime.h>
#include <hip/hip_bf16.h>
#include <stdint.h>

#define Bdim 32
#define Ldim 2048
#define Ddim 1024
#define Mdim (Bdim*Ldim)

typedef __attribute__((ext_vector_type(8))) short short8;
typedef __attribute__((ext_vector_type(8))) __bf16 bf16x8;
typedef __attribute__((ext_vector_type(4))) float f32x4;

__device__ __forceinline__ unsigned short f2bf(float v) {
    unsigned u = __float_as_uint(v);
    u += 0x7FFFu + ((u >> 16) & 1u);   // round-to-nearest-even
    return (unsigned short)(u >> 16);
}
__device__ __forceinline__ float bf2f(unsigned short h) {
    return __uint_as_float(((unsigned)h) << 16);
}
__device__ __forceinline__ void split2(float v, unsigned short& hi, unsigned short& lo) {
    hi = f2bf(v);
    float rem = v - bf2f(hi);          // exact (Dekker split)
    lo = f2bf(rem);
}

// ---------------- fp32 -> (bf16_hi, bf16_lo) split ----------------
__global__ __launch_bounds__(256) void k_split(const float* __restrict__ in,
        unsigned short* __restrict__ hi, unsigned short* __restrict__ lo, int n4) {
    int i = blockIdx.x*blockDim.x + threadIdx.x;
    int stride = gridDim.x*blockDim.x;
    for (; i < n4; i += stride) {
        float4 v = ((const float4*)in)[i];
        ushort4 h, l;
        split2(v.x, h.x, l.x);
        split2(v.y, h.y, l.y);
        split2(v.z, h.z, l.z);
        split2(v.w, h.w, l.w);
        ((ushort4*)hi)[i] = h;
        ((ushort4*)lo)[i] = l;
    }
}

// ---------------- split-bf16 GEMM:  C[m,e] = sum_d A[m,d]*W[e,d]  ----------------
// A: [M][1024] as hi/lo bf16.  W: [1024][1024] as hi/lo bf16 (row e, col d -> B^T form).
// mode 0: out = gamma[e]*(acc + bias[e])            (fp32, for scan)
// mode 1: out = acc + bias[e] + resid[m,e]          (fp32, final)
__global__ __launch_bounds__(256, 2) void k_gemm(
        const unsigned short* __restrict__ Ahi, const unsigned short* __restrict__ Alo,
        const unsigned short* __restrict__ Whi, const unsigned short* __restrict__ Wlo,
        const float* __restrict__ bias, const float* __restrict__ gamma,
        const float* __restrict__ resid, float* __restrict__ out, int mode) {
    // 4 tiles of [128][64] bf16 = 16KB each: 0=Ahi 1=Alo 2=Whi 3=Wlo
    __shared__ unsigned short lds[32768];
    const int tid  = threadIdx.x;
    const int w    = tid >> 6;
    const int lane = tid & 63;
    const int m0 = blockIdx.y * 128;
    const int n0 = blockIdx.x * 128;
    const int wr = w >> 1, wc = w & 1;     // 2x2 waves, each owns 64x64 of C

    // staging: wave w fully stages tile w (16 x 1KB global_load_lds)
    const unsigned short* src = (w==0)?Ahi:((w==1)?Alo:((w==2)?Whi:Wlo));
    const int rowbase = (w < 2) ? m0 : n0;
    const int lr = lane >> 3;          // row within 8-row chunk
    const int lc = (lane & 7) * 8;     // col (bf16 elems)

    f32x4 acc[4][4];
    #pragma unroll
    for (int i=0;i<4;++i)
      #pragma unroll
      for (int j=0;j<4;++j) acc[i][j] = (f32x4){0.f,0.f,0.f,0.f};

    const int row_a = lane & 15;           // A/B fragment row (m or n within 16-tile)
    const int ksel  = (lane >> 4) * 8;     // k sub-block per lane-quad

    for (int kt = 0; kt < Ddim/64; ++kt) {
        const int k0 = kt*64;
        #pragma unroll
        for (int i = 0; i < 16; ++i) {
            const unsigned short* gp = src + (size_t)(rowbase + i*8 + lr)*Ddim + (k0 + lc);
            unsigned short* lp = &lds[w*8192 + i*512];  // wave-uniform LDS base; HW adds lane*16B
            __builtin_amdgcn_global_load_lds(
                (const __attribute__((address_space(1))) void*)gp,
                (__attribute__((address_space(3))) void*)lp, 16, 0, 0);
        }
        __syncthreads();
        #pragma unroll
        for (int kk = 0; kk < 64; kk += 32) {
            short8 ah[4], al[4], bh[4], bl[4];
            #pragma unroll
            for (int f=0; f<4; ++f) {
                const int ar = wr*64 + f*16 + row_a;
                const int br = wc*64 + f*16 + row_a;
                ah[f] = *(const short8*)&lds[0*8192 + ar*64 + kk + ksel];
                al[f] = *(const short8*)&lds[1*8192 + ar*64 + kk + ksel];
                bh[f] = *(const short8*)&lds[2*8192 + br*64 + kk + ksel];
                bl[f] = *(const short8*)&lds[3*8192 + br*64 + kk + ksel];
            }
            #pragma unroll
            for (int mi=0; mi<4; ++mi) {
              #pragma unroll
              for (int ni=0; ni<4; ++ni) {
                acc[mi][ni] = __builtin_amdgcn_mfma_f32_16x16x32_bf16(
                    __builtin_bit_cast(bf16x8, ah[mi]), __builtin_bit_cast(bf16x8, bh[ni]),
                    acc[mi][ni], 0, 0, 0);
                acc[mi][ni] = __builtin_amdgcn_mfma_f32_16x16x32_bf16(
                    __builtin_bit_cast(bf16x8, ah[mi]), __builtin_bit_cast(bf16x8, bl[ni]),
                    acc[mi][ni], 0, 0, 0);
                acc[mi][ni] = __builtin_amdgcn_mfma_f32_16x16x32_bf16(
                    __builtin_bit_cast(bf16x8, al[mi]), __builtin_bit_cast(bf16x8, bh[ni]),
                    acc[mi][ni], 0, 0, 0);
              }
            }
        }
        __syncthreads();
    }

    // epilogue: C/D layout col=lane&15, row=(lane>>4)*4+reg  [verified m89/m91]
    const int crow0 = (lane >> 4) * 4;
    const int ccol  = lane & 15;
    #pragma unroll
    for (int mi=0; mi<4; ++mi) {
      #pragma unroll
      for (int ni=0; ni<4; ++ni) {
        const int col = n0 + wc*64 + ni*16 + ccol;
        const float bv = bias[col];
        const float gv = (mode == 0) ? gamma[col] : 1.f;
        #pragma unroll
        for (int r=0; r<4; ++r) {
          const int row = m0 + wr*64 + mi*16 + crow0 + r;
          const size_t idx = (size_t)row*Ddim + col;
          const float v = acc[mi][ni][r];
          if (mode == 0) out[idx] = gv * (v + bv);
          else           out[idx] = v + bv + resid[idx];
        }
      }
    }
}

// ---------------- diagonal recurrence scan: h_t = lam*h_{t-1} + gu_t ----------------
// one thread per (b,d) channel; writes y as hi/lo bf16 (GEMM2 A-operand)
__global__ __launch_bounds__(64) void k_scan(const float* __restrict__ gu,
        const float* __restrict__ lambda_log,
        unsigned short* __restrict__ yhi, unsigned short* __restrict__ ylo) {
    const int d = blockIdx.x*64 + threadIdx.x;
    const int b = blockIdx.y;
    const float lam = expf(lambda_log[d]);
    const size_t base = (size_t)b*Ldim*Ddim + d;
    float h = 0.f;
    for (int t0 = 0; t0 < Ldim; t0 += 16) {
        float g[16];
        #pragma unroll
        for (int j=0;j<16;++j) g[j] = gu[base + (size_t)(t0+j)*Ddim];
        #pragma unroll
        for (int j=0;j<16;++j) {
            h = fmaf(lam, h, g[j]);
            unsigned short hi, lo; split2(h, hi, lo);
            yhi[base + (size_t)(t0+j)*Ddim] = hi;
            ylo[base + (size_t)(t0+j)*Ddim] = lo;
        }
    }
}

extern "C" void kernel_launch(void* const* d_in, const int* in_sizes, int n_in,
                              void* d_out, int out_size, void* d_ws, size_t ws_size,
                              hipStream_t stream) {
    const float* x          = (const float*)d_in[0];
    const float* lambda_log = (const float*)d_in[1];
    const float* gamma      = (const float*)d_in[2];
    const float* W_in       = (const float*)d_in[3];
    const float* b_in       = (const float*)d_in[4];
    const float* W_out      = (const float*)d_in[5];
    const float* b_out      = (const float*)d_in[6];
    float* out = (float*)d_out;

    // workspace layout (~508 MiB):
    // xhi/xlo [M*D bf16 each] (reused as yhi/ylo after GEMM1), W splits, gu fp32
    unsigned short* xhi  = (unsigned short*)d_ws;
    unsigned short* xlo  = xhi  + (size_t)Mdim*Ddim;
    unsigned short* wihi = xlo  + (size_t)Mdim*Ddim;
    unsigned short* wilo = wihi + (size_t)Ddim*Ddim;
    unsigned short* wohi = wilo + (size_t)Ddim*Ddim;
    unsigned short* wolo = wohi + (size_t)Ddim*Ddim;
    float*          gu   = (float*)(wolo + (size_t)Ddim*Ddim);

    k_split<<<2048, 256, 0, stream>>>(x,     xhi,  xlo,  Mdim*Ddim/4);
    k_split<<<128,  256, 0, stream>>>(W_in,  wihi, wilo, Ddim*Ddim/4);
    k_split<<<128,  256, 0, stream>>>(W_out, wohi, wolo, Ddim*Ddim/4);

    // GEMM1: gu = gamma * (x @ W_in^T + b_in)
    k_gemm<<<dim3(Ddim/128, Mdim/128), 256, 0, stream>>>(
        xhi, xlo, wihi, wilo, b_in, gamma, nullptr, gu, 0);

    // scan -> y (hi/lo into x's split buffers; x itself no longer needed as bf16)
    k_scan<<<dim3(Ddim/64, Bdim), 64, 0, stream>>>(gu, lambda_log, xhi, xlo);

    // GEMM2: out = y @ W_out^T + b_out + x
    k_gemm<<<dim3(Ddim/128, Mdim/128), 256, 0, stream>>>(
        xhi, xlo, wohi, wolo, b_out, nullptr, x, out, 1);
}

// Round 2
// 1609.924 us; speedup vs baseline: 1.0657x; 1.0657x over previous
//
#include <hip/hip_runtime.h>
#include <hip/hip_bf16.h>
#include <stdint.h>

#define Bdim 32
#define Ldim 2048
#define Ddim 1024
#define Mdim (Bdim*Ldim)
#define NSEG 8
#define SEG  (Ldim/NSEG)   // 256

typedef __attribute__((ext_vector_type(8))) short short8;
typedef __attribute__((ext_vector_type(8))) __bf16 bf16x8;
typedef __attribute__((ext_vector_type(4))) float f32x4;

__device__ __forceinline__ unsigned short f2bf(float v) {
    unsigned u = __float_as_uint(v);
    u += 0x7FFFu + ((u >> 16) & 1u);   // round-to-nearest-even
    return (unsigned short)(u >> 16);
}
__device__ __forceinline__ float bf2f(unsigned short h) {
    return __uint_as_float(((unsigned)h) << 16);
}
__device__ __forceinline__ void split2(float v, unsigned short& hi, unsigned short& lo) {
    hi = f2bf(v);
    float rem = v - bf2f(hi);          // exact (Dekker split)
    lo = f2bf(rem);
}

// ---------------- fp32 -> (bf16_hi, bf16_lo) split ----------------
__global__ __launch_bounds__(256) void k_split(const float* __restrict__ in,
        unsigned short* __restrict__ hi, unsigned short* __restrict__ lo, int n4) {
    int i = blockIdx.x*blockDim.x + threadIdx.x;
    int stride = gridDim.x*blockDim.x;
    for (; i < n4; i += stride) {
        float4 v = ((const float4*)in)[i];
        ushort4 h, l;
        split2(v.x, h.x, l.x);
        split2(v.y, h.y, l.y);
        split2(v.z, h.z, l.z);
        split2(v.w, h.w, l.w);
        ((ushort4*)hi)[i] = h;
        ((ushort4*)lo)[i] = l;
    }
}

// ---------------- split-bf16 GEMM:  C[m,e] = sum_d A[m,d]*W[e,d]  ----------------
// T2 XOR-swizzled LDS (16B chunk ^= row&7), both-sides per rule #21:
//   linear global_load_lds dest + inverse-swizzled GLOBAL source + swizzled read.
// T1 XCD swizzle: blockIdx.x (=dispatch%8=XCD) carries m-row low bits so the 8
//   n-blocks sharing an A-tile land on ONE XCD's L2.
__global__ __launch_bounds__(256, 2) void k_gemm(
        const unsigned short* __restrict__ Ahi, const unsigned short* __restrict__ Alo,
        const unsigned short* __restrict__ Whi, const unsigned short* __restrict__ Wlo,
        const float* __restrict__ bias, const float* __restrict__ gamma,
        const float* __restrict__ resid, float* __restrict__ out, int mode) {
    // 4 tiles of [128][64] bf16 = 16KB each: 0=Ahi 1=Alo 2=Whi 3=Wlo
    __shared__ unsigned short lds[32768];
    const int tid  = threadIdx.x;
    const int w    = tid >> 6;
    const int lane = tid & 63;
    // XCD-aware remap (bijective): m_tile low 3 bits <- blockIdx.x
    const int m_t = (blockIdx.y & ~7u) | blockIdx.x;   // [0,512)
    const int n_t = blockIdx.y & 7u;                   // [0,8)
    const int m0 = m_t * 128;
    const int n0 = n_t * 128;
    const int wr = w >> 1, wc = w & 1;     // 2x2 waves, each owns 64x64 of C

    // staging: wave w fully stages tile w (16 x 1KB global_load_lds)
    const unsigned short* src = (w==0)?Ahi:((w==1)?Alo:((w==2)?Whi:Wlo));
    const int rowbase = (w < 2) ? m0 : n0;
    const int lr = lane >> 3;                      // row within 8-row chunk
    const int lc = ((lane & 7) ^ lr) * 8;          // inverse-swizzled source col chunk

    f32x4 acc[4][4];
    #pragma unroll
    for (int i=0;i<4;++i)
      #pragma unroll
      for (int j=0;j<4;++j) acc[i][j] = (f32x4){0.f,0.f,0.f,0.f};

    const int row_a = lane & 15;           // fragment row (m or n within 16-tile)
    const int kgrp  = lane >> 4;           // k sub-block group (0..3)
    const int l7    = lane & 7;            // == row&7 for all fragment rows

    for (int kt = 0; kt < Ddim/64; ++kt) {
        const int k0 = kt*64;
        #pragma unroll
        for (int i = 0; i < 16; ++i) {
            const unsigned short* gp = src + (size_t)(rowbase + i*8 + lr)*Ddim + (k0 + lc);
            unsigned short* lp = &lds[w*8192 + i*512];  // wave-uniform base; HW adds lane*16B
            __builtin_amdgcn_global_load_lds(
                (const __attribute__((address_space(1))) void*)gp,
                (__attribute__((address_space(3))) void*)lp, 16, 0, 0);
        }
        __syncthreads();
        #pragma unroll
        for (int kk = 0; kk < 64; kk += 32) {
            // physical 16B chunk = logical chunk ^ (row&7); row&7 == l7 for every f
            const int coff = (((kk >> 3) + kgrp) ^ l7) * 8;
            short8 ah[4], al[4], bh[4], bl[4];
            #pragma unroll
            for (int f=0; f<4; ++f) {
                const int ar = wr*64 + f*16 + row_a;
                const int br = wc*64 + f*16 + row_a;
                ah[f] = *(const short8*)&lds[0*8192 + ar*64 + coff];
                al[f] = *(const short8*)&lds[1*8192 + ar*64 + coff];
                bh[f] = *(const short8*)&lds[2*8192 + br*64 + coff];
                bl[f] = *(const short8*)&lds[3*8192 + br*64 + coff];
            }
            #pragma unroll
            for (int mi=0; mi<4; ++mi) {
              #pragma unroll
              for (int ni=0; ni<4; ++ni) {
                acc[mi][ni] = __builtin_amdgcn_mfma_f32_16x16x32_bf16(
                    __builtin_bit_cast(bf16x8, ah[mi]), __builtin_bit_cast(bf16x8, bh[ni]),
                    acc[mi][ni], 0, 0, 0);
                acc[mi][ni] = __builtin_amdgcn_mfma_f32_16x16x32_bf16(
                    __builtin_bit_cast(bf16x8, ah[mi]), __builtin_bit_cast(bf16x8, bl[ni]),
                    acc[mi][ni], 0, 0, 0);
                acc[mi][ni] = __builtin_amdgcn_mfma_f32_16x16x32_bf16(
                    __builtin_bit_cast(bf16x8, al[mi]), __builtin_bit_cast(bf16x8, bh[ni]),
                    acc[mi][ni], 0, 0, 0);
              }
            }
        }
        __syncthreads();
    }

    // epilogue: C/D layout col=lane&15, row=(lane>>4)*4+reg  [verified m89/m91]
    const int crow0 = (lane >> 4) * 4;
    const int ccol  = lane & 15;
    #pragma unroll
    for (int mi=0; mi<4; ++mi) {
      #pragma unroll
      for (int ni=0; ni<4; ++ni) {
        const int col = n0 + wc*64 + ni*16 + ccol;
        const float bv = bias[col];
        const float gv = (mode == 0) ? gamma[col] : 1.f;
        #pragma unroll
        for (int r=0; r<4; ++r) {
          const int row = m0 + wr*64 + mi*16 + crow0 + r;
          const size_t idx = (size_t)row*Ddim + col;
          const float v = acc[mi][ni][r];
          if (mode == 0) out[idx] = gv * (v + bv);
          else           out[idx] = v + bv + resid[idx];
        }
      }
    }
}

// ---------------- segmented diagonal recurrence ----------------
// λ^SEG <= 0.9^256 ~ 2e-12, so blocked scan == sequential scan numerically.
// k_scan1: per (b,d,seg) local reduction h_seg (h starts at 0)
__global__ __launch_bounds__(256) void k_scan1(const float* __restrict__ gu,
        const float* __restrict__ lambda_log, float* __restrict__ hseg) {
    const int d = blockIdx.x*256 + threadIdx.x;
    const int b = blockIdx.y;
    const int s = blockIdx.z;
    const float lam = expf(lambda_log[d]);
    const size_t base = (size_t)b*Ldim*Ddim + (size_t)s*SEG*Ddim + d;
    float h = 0.f;
    for (int t0 = 0; t0 < SEG; t0 += 8) {
        float g[8];
        #pragma unroll
        for (int j=0;j<8;++j) g[j] = gu[base + (size_t)(t0+j)*Ddim];
        #pragma unroll
        for (int j=0;j<8;++j) h = fmaf(lam, h, g[j]);
    }
    hseg[((size_t)s*Bdim + b)*Ddim + d] = h;
}

// k_scan2: carries entering each segment: c_0=0; c_s = λ^SEG·c_{s-1} + h_{s-1}
__global__ __launch_bounds__(256) void k_scan2(const float* __restrict__ hseg,
        const float* __restrict__ lambda_log, float* __restrict__ carry) {
    const int ch = blockIdx.x*256 + threadIdx.x;   // [0, B*D)
    const int b = ch >> 10;
    const int d = ch & 1023;
    const float lamS = expf(lambda_log[d] * (float)SEG);
    float c = 0.f;
    #pragma unroll
    for (int s = 0; s < NSEG; ++s) {
        carry[((size_t)s*Bdim + b)*Ddim + d] = c;
        c = fmaf(lamS, c, hseg[((size_t)s*Bdim + b)*Ddim + d]);
    }
}

// k_scan3: rescan each segment from its carry, write y as hi/lo bf16
__global__ __launch_bounds__(256) void k_scan3(const float* __restrict__ gu,
        const float* __restrict__ lambda_log, const float* __restrict__ carry,
        unsigned short* __restrict__ yhi, unsigned short* __restrict__ ylo) {
    const int d = blockIdx.x*256 + threadIdx.x;
    const int b = blockIdx.y;
    const int s = blockIdx.z;
    const float lam = expf(lambda_log[d]);
    const size_t base = (size_t)b*Ldim*Ddim + (size_t)s*SEG*Ddim + d;
    float h = carry[((size_t)s*Bdim + b)*Ddim + d];
    for (int t0 = 0; t0 < SEG; t0 += 8) {
        float g[8];
        #pragma unroll
        for (int j=0;j<8;++j) g[j] = gu[base + (size_t)(t0+j)*Ddim];
        #pragma unroll
        for (int j=0;j<8;++j) {
            h = fmaf(lam, h, g[j]);
            unsigned short hi, lo; split2(h, hi, lo);
            const size_t idx = base + (size_t)(t0+j)*Ddim;
            yhi[idx] = hi;
            ylo[idx] = lo;
        }
    }
}

extern "C" void kernel_launch(void* const* d_in, const int* in_sizes, int n_in,
                              void* d_out, int out_size, void* d_ws, size_t ws_size,
                              hipStream_t stream) {
    const float* x          = (const float*)d_in[0];
    const float* lambda_log = (const float*)d_in[1];
    const float* gamma      = (const float*)d_in[2];
    const float* W_in       = (const float*)d_in[3];
    const float* b_in       = (const float*)d_in[4];
    const float* W_out      = (const float*)d_in[5];
    const float* b_out      = (const float*)d_in[6];
    float* out = (float*)d_out;

    // workspace layout (~520 MiB):
    unsigned short* xhi  = (unsigned short*)d_ws;            // 128 MiB (reused as yhi)
    unsigned short* xlo  = xhi  + (size_t)Mdim*Ddim;         // 128 MiB (reused as ylo)
    unsigned short* wihi = xlo  + (size_t)Mdim*Ddim;         // 2 MiB
    unsigned short* wilo = wihi + (size_t)Ddim*Ddim;         // 2 MiB
    unsigned short* wohi = wilo + (size_t)Ddim*Ddim;         // 2 MiB
    unsigned short* wolo = wohi + (size_t)Ddim*Ddim;         // 2 MiB
    float*          gu   = (float*)(wolo + (size_t)Ddim*Ddim); // 256 MiB
    // hseg/carry (1 MiB each) alias the W_in split buffers — dead after GEMM1
    float* hseg  = (float*)wihi;
    float* carry = (float*)wilo;

    k_split<<<2048, 256, 0, stream>>>(x,     xhi,  xlo,  Mdim*Ddim/4);
    k_split<<<128,  256, 0, stream>>>(W_in,  wihi, wilo, Ddim*Ddim/4);
    k_split<<<128,  256, 0, stream>>>(W_out, wohi, wolo, Ddim*Ddim/4);

    // GEMM1: gu = gamma * (x @ W_in^T + b_in)
    k_gemm<<<dim3(8, Mdim/128), 256, 0, stream>>>(
        xhi, xlo, wihi, wilo, b_in, gamma, nullptr, gu, 0);

    // segmented scan -> y (hi/lo into x's split buffers, dead after GEMM1)
    k_scan1<<<dim3(Ddim/256, Bdim, NSEG), 256, 0, stream>>>(gu, lambda_log, hseg);
    k_scan2<<<(Bdim*Ddim)/256, 256, 0, stream>>>(hseg, lambda_log, carry);
    k_scan3<<<dim3(Ddim/256, Bdim, NSEG), 256, 0, stream>>>(gu, lambda_log, carry, xhi, xlo);

    // GEMM2: out = y @ W_out^T + b_out + x
    k_gemm<<<dim3(8, Mdim/128), 256, 0, stream>>>(
        xhi, xlo, wohi, wolo, b_out, nullptr, x, out, 1);
}

// Round 4
// 1498.147 us; speedup vs baseline: 1.1452x; 1.0746x over previous
//
#include <hip/hip_runtime.h>
#include <hip/hip_bf16.h>
#include <stdint.h>

#define Bdim 32
#define Ldim 2048
#define Ddim 1024
#define Mdim (Bdim*Ldim)
#define NSEG 8
#define SEG  (Ldim/NSEG)   // 256
#define WARM 128           // 0.9^128 = 1.4e-6

typedef __attribute__((ext_vector_type(8))) short short8;
typedef __attribute__((ext_vector_type(8))) __bf16 bf16x8;
typedef __attribute__((ext_vector_type(4))) float f32x4;

__device__ __forceinline__ unsigned short f2bf(float v) {
    unsigned u = __float_as_uint(v);
    u += 0x7FFFu + ((u >> 16) & 1u);   // round-to-nearest-even
    return (unsigned short)(u >> 16);
}
__device__ __forceinline__ float bf2f(unsigned short h) {
    return __uint_as_float(((unsigned)h) << 16);
}
__device__ __forceinline__ void split2(float v, unsigned short& hi, unsigned short& lo) {
    hi = f2bf(v);
    float rem = v - bf2f(hi);          // exact (Dekker split)
    lo = f2bf(rem);
}

// ---------------- fp32 -> (bf16_hi, bf16_lo) split ----------------
__global__ __launch_bounds__(256) void k_split(const float* __restrict__ in,
        unsigned short* __restrict__ hi, unsigned short* __restrict__ lo, int n4) {
    int i = blockIdx.x*blockDim.x + threadIdx.x;
    int stride = gridDim.x*blockDim.x;
    for (; i < n4; i += stride) {
        float4 v = ((const float4*)in)[i];
        ushort4 h, l;
        split2(v.x, h.x, l.x);
        split2(v.y, h.y, l.y);
        split2(v.z, h.z, l.z);
        split2(v.w, h.w, l.w);
        ((ushort4*)hi)[i] = h;
        ((ushort4*)lo)[i] = l;
    }
}

// ---------------- split-bf16 GEMM, 256x256 tile, BK=32, 8 waves ----------------
// C[m,e] = sum_d A[m,d]*W[e,d] via Ah*Wh + Ah*Wl + Al*Wh (fp32 MFMA accum).
// T3/T4: double-buffered LDS (128KB), STAGE issued at tile start, ONE
//   __syncthreads per K-tile (compiler emits the vmcnt drain there) -> loads
//   stay in flight across the whole tile's 4 MFMA phases.
// T5: setprio around each 24-MFMA cluster; sched_barrier(0) between phases.
// T2: XOR swizzle for 64B rows: phys_chunk = kgrp ^ ((row>>1)&3), applied
//   inverse on the GLOBAL source (linear gload_lds dest) + on ds_read addr.
// T1: XCD swizzle: blockIdx.x = m_t low bits; A-sharing blocks -> same XCD.
__global__ __launch_bounds__(512, 2) void k_gemm(
        const unsigned short* __restrict__ Ahi, const unsigned short* __restrict__ Alo,
        const unsigned short* __restrict__ Whi, const unsigned short* __restrict__ Wlo,
        const float* __restrict__ bias, const float* __restrict__ gamma,
        const float* __restrict__ resid, float* __restrict__ out, int mode) {
    // 2 bufs x {Ahi,Alo,Whi,Wlo}[256][32] bf16 = 128 KB
    __shared__ unsigned short lds[65536];
    const int tid  = threadIdx.x;
    const int w    = tid >> 6;
    const int lane = tid & 63;
    const int m_t = ((blockIdx.y >> 2) << 3) | blockIdx.x;   // [0,256)
    const int n_t = blockIdx.y & 3;                           // [0,4)
    const int m0 = m_t * 256;
    const int n0 = n_t * 256;
    const int wr = w >> 2, wc = w & 3;    // wave owns rows wr*128.., cols wc*64..

    // ---- staging setup: wave pair (2k,2k+1) stages tensor k, 8 instrs each
    const int tens = w >> 1;
    const unsigned short* src = (tens==0)?Ahi:((tens==1)?Alo:((tens==2)?Whi:Wlo));
    const int rowbase = ((tens < 2) ? m0 : n0) + (w & 1) * 128;
    const int s_lr = lane >> 2;                              // row in 16-row group
    const int s_gc = ((lane & 3) ^ ((lane >> 3) & 3)) * 8;   // inverse-swizzled src chunk
    const int s_lds = tens * 8192 + (w & 1) * 4096;          // ushort offset, linear dest

    // ---- fragment read setup
    const int r15 = lane & 15;
    const int pc8 = ((lane >> 4) ^ ((lane >> 1) & 3)) * 8;   // swizzled chunk (elems)

    f32x4 acc[8][4];
    #pragma unroll
    for (int i=0;i<8;++i)
      #pragma unroll
      for (int j=0;j<4;++j) acc[i][j] = (f32x4){0.f,0.f,0.f,0.f};

    #define STAGE(dbuf, kt) do {                                                  \
        const unsigned short* g0 = src + (size_t)(rowbase + s_lr)*Ddim + (kt)*32 + s_gc; \
        _Pragma("unroll")                                                         \
        for (int i_ = 0; i_ < 8; ++i_) {                                          \
            __builtin_amdgcn_global_load_lds(                                     \
                (const __attribute__((address_space(1))) void*)(g0 + (size_t)i_*16*Ddim), \
                (__attribute__((address_space(3))) void*)&lds[(dbuf)*32768 + s_lds + i_*512], \
                16, 0, 0);                                                        \
        }                                                                         \
    } while(0)

    STAGE(0, 0);
    __syncthreads();

    #pragma unroll 1
    for (int kt = 0; kt < 32; ++kt) {
        const int p = kt & 1;
        const int P = p * 32768;
        if (kt + 1 < 32) STAGE(p ^ 1, kt + 1);   // in flight across all 4 phases

        short8 b[4][2], a[8][2];
        #pragma unroll
        for (int n = 0; n < 4; ++n)
          #pragma unroll
          for (int h = 0; h < 2; ++h)
            b[n][h] = *(const short8*)&lds[P + 16384 + h*8192 + (wc*64 + n*16 + r15)*32 + pc8];
        #pragma unroll
        for (int m = 0; m < 2; ++m)
          #pragma unroll
          for (int h = 0; h < 2; ++h)
            a[m][h] = *(const short8*)&lds[P + h*8192 + (wr*128 + m*16 + r15)*32 + pc8];

        #pragma unroll
        for (int q = 0; q < 4; ++q) {
            if (q < 3) {   // prefetch next phase's A pair (rotated reads)
                #pragma unroll
                for (int mm = 0; mm < 2; ++mm)
                  #pragma unroll
                  for (int h = 0; h < 2; ++h)
                    a[(q+1)*2+mm][h] = *(const short8*)
                        &lds[P + h*8192 + (wr*128 + ((q+1)*2+mm)*16 + r15)*32 + pc8];
            }
            __builtin_amdgcn_s_setprio(1);
            #pragma unroll
            for (int mm = 0; mm < 2; ++mm) {
              const int m = q*2 + mm;
              #pragma unroll
              for (int n = 0; n < 4; ++n) {
                acc[m][n] = __builtin_amdgcn_mfma_f32_16x16x32_bf16(
                    __builtin_bit_cast(bf16x8, a[m][0]), __builtin_bit_cast(bf16x8, b[n][0]),
                    acc[m][n], 0, 0, 0);
                acc[m][n] = __builtin_amdgcn_mfma_f32_16x16x32_bf16(
                    __builtin_bit_cast(bf16x8, a[m][0]), __builtin_bit_cast(bf16x8, b[n][1]),
                    acc[m][n], 0, 0, 0);
                acc[m][n] = __builtin_amdgcn_mfma_f32_16x16x32_bf16(
                    __builtin_bit_cast(bf16x8, a[m][1]), __builtin_bit_cast(bf16x8, b[n][0]),
                    acc[m][n], 0, 0, 0);
              }
            }
            __builtin_amdgcn_s_setprio(0);
            __builtin_amdgcn_sched_barrier(0);
        }
        __syncthreads();   // drains this tile's STAGE (vmcnt) + read/write fence
    }
    #undef STAGE

    // epilogue: C/D layout col=lane&15, row=(lane>>4)*4+reg  [verified m89/m91]
    const int crow0 = (lane >> 4) * 4;
    #pragma unroll
    for (int m = 0; m < 8; ++m) {
      #pragma unroll
      for (int n = 0; n < 4; ++n) {
        const int col = n0 + wc*64 + n*16 + r15;
        const float bv = bias[col];
        const float gv = (mode == 0) ? gamma[col] : 1.f;
        #pragma unroll
        for (int r = 0; r < 4; ++r) {
          const int row = m0 + wr*128 + m*16 + crow0 + r;
          const size_t idx = (size_t)row*Ddim + col;
          const float v = acc[m][n][r];
          if (mode == 0) out[idx] = gv * (v + bv);
          else           out[idx] = v + bv + resid[idx];
        }
      }
    }
}

// ---------------- scan with warm-up window (single pass) ----------------
// h_t depends on history through lam^k; lam^128 <= 0.9^128 = 1.4e-6, so each
// 256-step segment scanned after a 128-step warm-up matches the sequential
// scan to ~2e-5 absolute. One gu read (1.44x) + one y write.
__global__ __launch_bounds__(256) void k_scan(const float* __restrict__ gu,
        const float* __restrict__ lambda_log,
        unsigned short* __restrict__ yhi, unsigned short* __restrict__ ylo) {
    const int d = blockIdx.x*256 + threadIdx.x;
    const int b = blockIdx.y;
    const int s = blockIdx.z;
    const float lam = expf(lambda_log[d]);
    const size_t cb = (size_t)b*Ldim*Ddim + d;
    const int t0 = s * SEG;
    float h = 0.f;
    if (s > 0) {                       // uniform per block (s = blockIdx.z)
        const size_t wb = cb + (size_t)(t0 - WARM)*Ddim;
        for (int j = 0; j < WARM; j += 8) {
            float g[8];
            #pragma unroll
            for (int k=0;k<8;++k) g[k] = gu[wb + (size_t)(j+k)*Ddim];
            #pragma unroll
            for (int k=0;k<8;++k) h = fmaf(lam, h, g[k]);
        }
    }
    const size_t sb = cb + (size_t)t0*Ddim;
    for (int j = 0; j < SEG; j += 8) {
        float g[8];
        #pragma unroll
        for (int k=0;k<8;++k) g[k] = gu[sb + (size_t)(j+k)*Ddim];
        #pragma unroll
        for (int k=0;k<8;++k) {
            h = fmaf(lam, h, g[k]);
            unsigned short hi, lo; split2(h, hi, lo);
            const size_t idx = sb + (size_t)(j+k)*Ddim;
            yhi[idx] = hi;
            ylo[idx] = lo;
        }
    }
}

extern "C" void kernel_launch(void* const* d_in, const int* in_sizes, int n_in,
                              void* d_out, int out_size, void* d_ws, size_t ws_size,
                              hipStream_t stream) {
    const float* x          = (const float*)d_in[0];
    const float* lambda_log = (const float*)d_in[1];
    const float* gamma      = (const float*)d_in[2];
    const float* W_in       = (const float*)d_in[3];
    const float* b_in       = (const float*)d_in[4];
    const float* W_out      = (const float*)d_in[5];
    const float* b_out      = (const float*)d_in[6];
    float* out = (float*)d_out;

    // workspace layout (~520 MiB)
    unsigned short* xhi  = (unsigned short*)d_ws;              // 128 MiB (reused as yhi)
    unsigned short* xlo  = xhi  + (size_t)Mdim*Ddim;           // 128 MiB (reused as ylo)
    unsigned short* wihi = xlo  + (size_t)Mdim*Ddim;           // 2 MiB
    unsigned short* wilo = wihi + (size_t)Ddim*Ddim;           // 2 MiB
    unsigned short* wohi = wilo + (size_t)Ddim*Ddim;           // 2 MiB
    unsigned short* wolo = wohi + (size_t)Ddim*Ddim;           // 2 MiB
    float*          gu   = (float*)(wolo + (size_t)Ddim*Ddim); // 256 MiB

    k_split<<<2048, 256, 0, stream>>>(x,     xhi,  xlo,  Mdim*Ddim/4);
    k_split<<<128,  256, 0, stream>>>(W_in,  wihi, wilo, Ddim*Ddim/4);
    k_split<<<128,  256, 0, stream>>>(W_out, wohi, wolo, Ddim*Ddim/4);

    // GEMM1: gu = gamma * (x @ W_in^T + b_in)
    k_gemm<<<dim3(8, 128), 512, 0, stream>>>(
        xhi, xlo, wihi, wilo, b_in, gamma, nullptr, gu, 0);

    // scan -> y (hi/lo into x's split buffers, dead after GEMM1)
    k_scan<<<dim3(Ddim/256, Bdim, NSEG), 256, 0, stream>>>(gu, lambda_log, xhi, xlo);

    // GEMM2: out = y @ W_out^T + b_out + x
    k_gemm<<<dim3(8, 128), 512, 0, stream>>>(
        xhi, xlo, wohi, wolo, b_out, nullptr, x, out, 1);
}

// Round 7
// 1444.196 us; speedup vs baseline: 1.1879x; 1.0374x over previous
//
#include <hip/hip_runtime.h>
#include <hip/hip_bf16.h>
#include <stdint.h>

#define Bdim 32
#define Ldim 2048
#define Ddim 1024
#define Mdim (Bdim*Ldim)
#define NSEG 8
#define SEG  (Ldim/NSEG)   // 256
#define WARM 128           // 0.9^128 = 1.4e-6

typedef __attribute__((ext_vector_type(8))) short short8;
typedef __attribute__((ext_vector_type(8))) __bf16 bf16x8;
typedef __attribute__((ext_vector_type(4))) float f32x4;

__device__ __forceinline__ unsigned short f2bf(float v) {
    unsigned u = __float_as_uint(v);
    u += 0x7FFFu + ((u >> 16) & 1u);   // round-to-nearest-even
    return (unsigned short)(u >> 16);
}
__device__ __forceinline__ float bf2f(unsigned short h) {
    return __uint_as_float(((unsigned)h) << 16);
}
__device__ __forceinline__ void split2(float v, unsigned short& hi, unsigned short& lo) {
    hi = f2bf(v);
    float rem = v - bf2f(hi);          // exact (Dekker split)
    lo = f2bf(rem);
}

// ---------------- fp32 -> (bf16_hi, bf16_lo) split ----------------
__global__ __launch_bounds__(256) void k_split(const float* __restrict__ in,
        unsigned short* __restrict__ hi, unsigned short* __restrict__ lo, int n4) {
    int i = blockIdx.x*blockDim.x + threadIdx.x;
    int stride = gridDim.x*blockDim.x;
    for (; i < n4; i += stride) {
        float4 v = ((const float4*)in)[i];
        ushort4 h, l;
        split2(v.x, h.x, l.x);
        split2(v.y, h.y, l.y);
        split2(v.z, h.z, l.z);
        split2(v.w, h.w, l.w);
        ((ushort4*)hi)[i] = h;
        ((ushort4*)lo)[i] = l;
    }
}

// ======== split-bf16 GEMM, 256x256 tile, BK=32, 8 waves, counted-vmcnt ========
// 3 phases per K-tile, organized by PRODUCT (Ah*Wh, Ah*Wl, Al*Wh) so A-frags
// are reused in-register. Staging: all 512 threads stage each 16KB tensor
// quarter (2 gload_lds/wave); issue order per tile: Ah, Wh, Wl, Al, spread
// over the 3 phases -> per-wave queue gives uniform vmcnt(4) at every phase,
// NEVER 0 in the main loop (T4). Raw s_barrier (no drain), lgkmcnt(0)+
// sched_barrier(0) before MFMA (rule #18), setprio around MFMA cluster (T5).
// T2 swizzle: phys 16B chunk = logical ^ ((row>>1)&3), inverse on global src.
// T1: blockIdx.x = m_t low 3 bits (XCD) so A-sharing blocks share one L2.
#define VMW(N) asm volatile("s_waitcnt vmcnt(" #N ")" ::: "memory")
#define LGKM0() do { asm volatile("s_waitcnt lgkmcnt(0)" ::: "memory"); \
                     __builtin_amdgcn_sched_barrier(0); } while(0)

__global__ __launch_bounds__(512, 2) void k_gemm(
        const unsigned short* __restrict__ Ahi, const unsigned short* __restrict__ Alo,
        const unsigned short* __restrict__ Whi, const unsigned short* __restrict__ Wlo,
        const float* __restrict__ bias, const float* __restrict__ gamma,
        const float* __restrict__ resid, float* __restrict__ out, int mode) {
    // 2 bufs x {Ah,Al,Wh,Wl}[256][32] bf16 = 128 KB
    __shared__ unsigned short lds[65536];
    const int tid  = threadIdx.x;
    const int w    = tid >> 6;
    const int lane = tid & 63;
    const int m_t = ((blockIdx.y >> 2) << 3) | blockIdx.x;   // [0,256)
    const int n_t = blockIdx.y & 3;                           // [0,4)
    const int m0 = m_t * 256;
    const int n0 = n_t * 256;
    const int wr = w >> 2, wc = w & 3;    // wave tile: rows wr*128.., cols wc*64..

    // ---- staging: thread covers row s_row (+128 in round 2), phys chunk tid&3
    const int s_row = tid >> 2;                              // 0..127
    const int s_gc  = ((tid & 3) ^ ((tid >> 3) & 3)) * 8;    // inverse-swizzled src chunk
    const int s_off = w * 512;                               // wave-uniform dest (ushorts)
    const unsigned short* gAh = Ahi + (size_t)(m0 + s_row)*Ddim + s_gc;
    const unsigned short* gAl = Alo + (size_t)(m0 + s_row)*Ddim + s_gc;
    const unsigned short* gWh = Whi + (size_t)(n0 + s_row)*Ddim + s_gc;
    const unsigned short* gWl = Wlo + (size_t)(n0 + s_row)*Ddim + s_gc;

    // LDS tensor offsets (ushorts): Ah=0, Al=8192, Wh=16384, Wl=24576
    #define STG(dbuf, kt, TOFF, GP) do {                                          \
        unsigned short* l0 = &lds[(dbuf)*32768 + (TOFF) + s_off];                 \
        const unsigned short* g0 = (GP) + (kt)*32;                                \
        __builtin_amdgcn_global_load_lds(                                         \
            (const __attribute__((address_space(1))) void*)g0,                    \
            (__attribute__((address_space(3))) void*)l0, 16, 0, 0);               \
        __builtin_amdgcn_global_load_lds(                                         \
            (const __attribute__((address_space(1))) void*)(g0 + (size_t)128*Ddim),\
            (__attribute__((address_space(3))) void*)(l0 + 4096), 16, 0, 0);      \
    } while(0)

    // ---- fragment read setup
    const int r15 = lane & 15;
    const int pc8 = ((lane >> 4) ^ ((lane >> 1) & 3)) * 8;   // swizzled chunk (elems)
    #define RD_B(DST, TOFF) do { _Pragma("unroll")                                \
        for (int n_=0;n_<4;++n_) (DST)[n_] = *(const short8*)                     \
            &lds[P + (TOFF) + (wc*64 + n_*16 + r15)*32 + pc8]; } while(0)
    #define RD_A(DST, TOFF) do { _Pragma("unroll")                                \
        for (int m_=0;m_<8;++m_) (DST)[m_] = *(const short8*)                     \
            &lds[P + (TOFF) + (wr*128 + m_*16 + r15)*32 + pc8]; } while(0)
    #define MFMA_BLOCK(AF, BF) do {                                               \
        __builtin_amdgcn_s_setprio(1);                                            \
        _Pragma("unroll")                                                         \
        for (int m_=0;m_<8;++m_) {                                                \
          _Pragma("unroll")                                                       \
          for (int n_=0;n_<4;++n_) {                                              \
            acc[m_][n_] = __builtin_amdgcn_mfma_f32_16x16x32_bf16(                \
                __builtin_bit_cast(bf16x8, (AF)[m_]),                             \
                __builtin_bit_cast(bf16x8, (BF)[n_]), acc[m_][n_], 0, 0, 0);      \
          }                                                                       \
        }                                                                         \
        __builtin_amdgcn_s_setprio(0);                                            \
    } while(0)

    f32x4 acc[8][4];
    #pragma unroll
    for (int i=0;i<8;++i)
      #pragma unroll
      for (int j=0;j<4;++j) acc[i][j] = (f32x4){0.f,0.f,0.f,0.f};
    short8 af[8], bf[4], cf[4];

    // prologue: stage tile 0, queue order [Ah, Wh, Wl, Al]
    STG(0, 0, 0,     gAh);
    STG(0, 0, 16384, gWh);
    STG(0, 0, 24576, gWl);
    STG(0, 0, 8192,  gAl);

    #pragma unroll 1
    for (int kt = 0; kt < 31; ++kt) {
        const int P = (kt & 1) * 32768;
        const int Q = (kt & 1) ^ 1;
        // phase 0: needs Ah(t),Wh(t) = oldest 4 of 8 outstanding
        VMW(4); __builtin_amdgcn_s_barrier();
        RD_B(bf, 16384);
        RD_A(af, 0);
        STG(Q, kt+1, 0, gAh);
        LGKM0();
        MFMA_BLOCK(af, bf);
        // phase 1: needs Wl(t) = oldest 2 of 6
        VMW(4); __builtin_amdgcn_s_barrier();
        RD_B(cf, 24576);
        STG(Q, kt+1, 16384, gWh);
        LGKM0();
        MFMA_BLOCK(af, cf);
        // phase 2: needs Al(t) = oldest 2 of 6
        VMW(4); __builtin_amdgcn_s_barrier();
        RD_A(af, 8192);                    // Al overwrites Ah regs (dead)
        STG(Q, kt+1, 24576, gWl);
        STG(Q, kt+1, 8192,  gAl);
        LGKM0();
        MFMA_BLOCK(af, bf);
    }
    {   // peeled last tile (kt=31, P=32768): no staging, draining waits
        const int P = 32768;
        VMW(4); __builtin_amdgcn_s_barrier();
        RD_B(bf, 16384);
        RD_A(af, 0);
        LGKM0();
        MFMA_BLOCK(af, bf);
        VMW(2); __builtin_amdgcn_s_barrier();
        RD_B(cf, 24576);
        LGKM0();
        MFMA_BLOCK(af, cf);
        VMW(0); __builtin_amdgcn_s_barrier();
        RD_A(af, 8192);
        LGKM0();
        MFMA_BLOCK(af, bf);
    }
    #undef STG
    #undef RD_A
    #undef RD_B
    #undef MFMA_BLOCK

    // epilogue: C/D layout col=lane&15, row=(lane>>4)*4+reg  [verified m89/m91]
    const int crow0 = (lane >> 4) * 4;
    #pragma unroll
    for (int m = 0; m < 8; ++m) {
      #pragma unroll
      for (int n = 0; n < 4; ++n) {
        const int col = n0 + wc*64 + n*16 + r15;
        const float bv = bias[col];
        const float gv = (mode == 0) ? gamma[col] : 1.f;
        #pragma unroll
        for (int r = 0; r < 4; ++r) {
          const int row = m0 + wr*128 + m*16 + crow0 + r;
          const size_t idx = (size_t)row*Ddim + col;
          const float v = acc[m][n][r];
          if (mode == 0) out[idx] = gv * (v + bv);
          else           out[idx] = v + bv + resid[idx];
        }
      }
    }
}

// ---------------- scan with warm-up window (single pass, float2) ----------------
// lam^128 <= 0.9^128 = 1.4e-6: each 256-step segment scanned after a 128-step
// warm-up matches the exact scan to ~2e-5. Two channels per thread (8B loads).
__global__ __launch_bounds__(256) void k_scan(const float* __restrict__ gu,
        const float* __restrict__ lambda_log,
        unsigned short* __restrict__ yhi, unsigned short* __restrict__ ylo) {
    const int d = (blockIdx.x*256 + threadIdx.x) * 2;
    const int b = blockIdx.y;
    const int s = blockIdx.z;
    const float lam0 = expf(lambda_log[d]);
    const float lam1 = expf(lambda_log[d+1]);
    const size_t cb = (size_t)b*Ldim*Ddim + d;
    const int t0 = s * SEG;
    float h0 = 0.f, h1 = 0.f;
    if (s > 0) {                       // uniform per block (s = blockIdx.z)
        const size_t wb = cb + (size_t)(t0 - WARM)*Ddim;
        for (int j = 0; j < WARM; j += 8) {
            float2 g[8];
            #pragma unroll
            for (int k=0;k<8;++k) g[k] = *(const float2*)&gu[wb + (size_t)(j+k)*Ddim];
            #pragma unroll
            for (int k=0;k<8;++k) { h0 = fmaf(lam0, h0, g[k].x); h1 = fmaf(lam1, h1, g[k].y); }
        }
    }
    const size_t sb = cb + (size_t)t0*Ddim;
    for (int j = 0; j < SEG; j += 8) {
        float2 g[8];
        #pragma unroll
        for (int k=0;k<8;++k) g[k] = *(const float2*)&gu[sb + (size_t)(j+k)*Ddim];
        #pragma unroll
        for (int k=0;k<8;++k) {
            h0 = fmaf(lam0, h0, g[k].x);
            h1 = fmaf(lam1, h1, g[k].y);
            unsigned short hi0, lo0, hi1, lo1;
            split2(h0, hi0, lo0);
            split2(h1, hi1, lo1);
            const size_t idx = sb + (size_t)(j+k)*Ddim;
            *(unsigned*)&yhi[idx] = (unsigned)hi0 | ((unsigned)hi1 << 16);
            *(unsigned*)&ylo[idx] = (unsigned)lo0 | ((unsigned)lo1 << 16);
        }
    }
}

extern "C" void kernel_launch(void* const* d_in, const int* in_sizes, int n_in,
                              void* d_out, int out_size, void* d_ws, size_t ws_size,
                              hipStream_t stream) {
    const float* x          = (const float*)d_in[0];
    const float* lambda_log = (const float*)d_in[1];
    const float* gamma      = (const float*)d_in[2];
    const float* W_in       = (const float*)d_in[3];
    const float* b_in       = (const float*)d_in[4];
    const float* W_out      = (const float*)d_in[5];
    const float* b_out      = (const float*)d_in[6];
    float* out = (float*)d_out;

    // workspace layout (~520 MiB)
    unsigned short* xhi  = (unsigned short*)d_ws;              // 128 MiB (reused as yhi)
    unsigned short* xlo  = xhi  + (size_t)Mdim*Ddim;           // 128 MiB (reused as ylo)
    unsigned short* wihi = xlo  + (size_t)Mdim*Ddim;           // 2 MiB
    unsigned short* wilo = wihi + (size_t)Ddim*Ddim;           // 2 MiB
    unsigned short* wohi = wilo + (size_t)Ddim*Ddim;           // 2 MiB
    unsigned short* wolo = wohi + (size_t)Ddim*Ddim;           // 2 MiB
    float*          gu   = (float*)(wolo + (size_t)Ddim*Ddim); // 256 MiB

    k_split<<<2048, 256, 0, stream>>>(x,     xhi,  xlo,  Mdim*Ddim/4);
    k_split<<<128,  256, 0, stream>>>(W_in,  wihi, wilo, Ddim*Ddim/4);
    k_split<<<128,  256, 0, stream>>>(W_out, wohi, wolo, Ddim*Ddim/4);

    // GEMM1: gu = gamma * (x @ W_in^T + b_in)
    k_gemm<<<dim3(8, 128), 512, 0, stream>>>(
        xhi, xlo, wihi, wilo, b_in, gamma, nullptr, gu, 0);

    // scan -> y (hi/lo into x's split buffers, dead after GEMM1)
    k_scan<<<dim3(2, Bdim, NSEG), 256, 0, stream>>>(gu, lambda_log, xhi, xlo);

    // GEMM2: out = y @ W_out^T + b_out + x
    k_gemm<<<dim3(8, 128), 512, 0, stream>>>(
        xhi, xlo, wohi, wolo, b_out, nullptr, x, out, 1);
}